// Round 2
// baseline (476.058 us; speedup 1.0000x reference)
//
#include <hip/hip_runtime.h>

#define NEG 0.2f

// ======================================================================
// K1: xl = x @ W^T  (fp32, K-tiled LDS GEMM), fused per-node scores
//     aj[n,h] = sum_c xl[n,h,c]*attn_j[h,c],  ai likewise.
// Block 256 thr, tile 64 rows x 128 cols, K-step 64.
// Thread (tc=tid&15, tr=tid>>4) computes rows tr*4..+3 and columns
// {4tc..4tc+3} and {64+4tc..64+4tc+3}  (stride-4 LDS reads: 2-way = free).
// ======================================================================
__global__ __launch_bounds__(256, 2) void gemm_node(
    const float* __restrict__ x, const float* __restrict__ W,
    const float* __restrict__ attn_j, const float* __restrict__ attn_i,
    float* __restrict__ xl, float* __restrict__ aj, float* __restrict__ ai,
    int N)
{
  __shared__ float wt[64][132];   // wt[k][m] = W[m][kt+k]
  __shared__ float xs[64][68];    // xs[r][k] = x[r0+r][kt+k]
  const int tid = threadIdx.x;
  const int r0 = blockIdx.x * 64;
  const int tc = tid & 15;
  const int tr = tid >> 4;

  float acc[4][8];
  #pragma unroll
  for (int i = 0; i < 4; ++i)
    #pragma unroll
    for (int j = 0; j < 8; ++j) acc[i][j] = 0.f;

  for (int kt = 0; kt < 128; kt += 64) {
    __syncthreads();
    // stage W[*, kt..kt+63] transposed: 128 rows x 16 float4
    #pragma unroll
    for (int it = 0; it < 8; ++it) {
      int id = tid + 256 * it;          // 0..2047
      int m  = id >> 4;                 // 0..127
      int k4 = id & 15;                 // 0..15
      float4 w4 = ((const float4*)W)[(size_t)m * 32 + (kt >> 2) + k4];
      wt[k4 * 4 + 0][m] = w4.x;
      wt[k4 * 4 + 1][m] = w4.y;
      wt[k4 * 4 + 2][m] = w4.z;
      wt[k4 * 4 + 3][m] = w4.w;
    }
    // stage x tile: 64 rows x 16 float4
    #pragma unroll
    for (int it = 0; it < 4; ++it) {
      int id = tid + 256 * it;          // 0..1023
      int r  = id >> 4;
      int k4 = id & 15;
      int row = r0 + r;
      float4 v = make_float4(0.f, 0.f, 0.f, 0.f);
      if (row < N) v = ((const float4*)x)[(size_t)row * 32 + (kt >> 2) + k4];
      *(float4*)&xs[r][k4 * 4] = v;
    }
    __syncthreads();

    #pragma unroll 2
    for (int k = 0; k < 64; ++k) {
      float4 wa = *(const float4*)&wt[k][tc * 4];        // cols 4tc..+3
      float4 wb = *(const float4*)&wt[k][64 + tc * 4];   // cols 64+4tc..+3
      #pragma unroll
      for (int i = 0; i < 4; ++i) {
        float xv = xs[tr * 4 + i][k];
        acc[i][0] = fmaf(xv, wa.x, acc[i][0]);
        acc[i][1] = fmaf(xv, wa.y, acc[i][1]);
        acc[i][2] = fmaf(xv, wa.z, acc[i][2]);
        acc[i][3] = fmaf(xv, wa.w, acc[i][3]);
        acc[i][4] = fmaf(xv, wb.x, acc[i][4]);
        acc[i][5] = fmaf(xv, wb.y, acc[i][5]);
        acc[i][6] = fmaf(xv, wb.z, acc[i][6]);
        acc[i][7] = fmaf(xv, wb.w, acc[i][7]);
      }
    }
  }

  // epilogue: write xl + fused per-node head scores.
  // cols of acc[i][j]: j<4 -> 4tc+j (head h0=tc>>3), j>=4 -> 64+4tc+j-4 (head h1=2+h0)
  const int h0 = tc >> 3;
  const int h1 = 2 + h0;
  const int cb = 4 * (tc & 7);        // offset within head
  #pragma unroll
  for (int i = 0; i < 4; ++i) {
    int row = r0 + tr * 4 + i;
    float pj0 = 0.f, pi0 = 0.f, pj1 = 0.f, pi1 = 0.f;
    #pragma unroll
    for (int j = 0; j < 4; ++j) {
      pj0 = fmaf(acc[i][j],     attn_j[h0 * 32 + cb + j], pj0);
      pi0 = fmaf(acc[i][j],     attn_i[h0 * 32 + cb + j], pi0);
      pj1 = fmaf(acc[i][4 + j], attn_j[h1 * 32 + cb + j], pj1);
      pi1 = fmaf(acc[i][4 + j], attn_i[h1 * 32 + cb + j], pi1);
    }
    // reduce over the 8 lanes (tid bits 0..2) covering each head's 32 channels
    #pragma unroll
    for (int mask = 1; mask < 8; mask <<= 1) {
      pj0 += __shfl_xor(pj0, mask);
      pi0 += __shfl_xor(pi0, mask);
      pj1 += __shfl_xor(pj1, mask);
      pi1 += __shfl_xor(pi1, mask);
    }
    if (row < N) {
      float4 o0 = make_float4(acc[i][0], acc[i][1], acc[i][2], acc[i][3]);
      float4 o1 = make_float4(acc[i][4], acc[i][5], acc[i][6], acc[i][7]);
      ((float4*)xl)[(size_t)row * 32 + tc]      = o0;
      ((float4*)xl)[(size_t)row * 32 + 16 + tc] = o1;
      if ((tid & 7) == 0) {
        aj[row * 4 + h0] = pj0;
        ai[row * 4 + h0] = pi0;
        aj[row * 4 + h1] = pj1;
        ai[row * 4 + h1] = pi1;
      }
    }
  }
}

// ======================================================================
// K2: double-gather resolution + degree init (self-loop = 1):
//     bj[n] = aj[src[n]], bi[n] = ai[dst[n]], deg[n] = 1
// ======================================================================
__global__ __launch_bounds__(256) void node_prep(
    const float* __restrict__ aj, const float* __restrict__ ai,
    const int* __restrict__ src, const int* __restrict__ dst,
    float* __restrict__ bj, float* __restrict__ bi,
    int* __restrict__ deg, int N)
{
  int n = blockIdx.x * blockDim.x + threadIdx.x;
  if (n >= N) return;
  ((float4*)bj)[n] = ((const float4*)aj)[src[n]];
  ((float4*)bi)[n] = ((const float4*)ai)[dst[n]];
  deg[n] = 1;
}

// ======================================================================
// K3: in-degree histogram
// ======================================================================
__global__ __launch_bounds__(256) void hist(const int* __restrict__ dst,
                                            int* __restrict__ deg, int E) {
  int e = blockIdx.x * blockDim.x + threadIdx.x;
  if (e < E) atomicAdd(&deg[dst[e]], 1);
}

// ======================================================================
// K4: single-block exclusive prefix scan (off + cursor)
// ======================================================================
__global__ __launch_bounds__(1024) void scan_kernel(
    const int* __restrict__ deg, int* __restrict__ off,
    int* __restrict__ cursor, int N)
{
  __shared__ int wsum[16];
  __shared__ int carry_s;
  const int tid  = threadIdx.x;
  const int lane = tid & 63;
  const int w    = tid >> 6;
  if (tid == 0) carry_s = 0;
  __syncthreads();
  for (int base = 0; base < N; base += 1024) {
    int i = base + tid;
    int v = (i < N) ? deg[i] : 0;
    int xv = v;
    #pragma unroll
    for (int d = 1; d < 64; d <<= 1) {
      int y = __shfl_up(xv, d);
      if (lane >= d) xv += y;
    }
    if (lane == 63) wsum[w] = xv;
    __syncthreads();
    if (w == 0) {
      int s = (lane < 16) ? wsum[lane] : 0;
      #pragma unroll
      for (int d = 1; d < 16; d <<= 1) {
        int y = __shfl_up(s, d);
        if (lane >= d) s += y;
      }
      if (lane < 16) wsum[lane] = s;
    }
    __syncthreads();
    int wpre = (w > 0) ? wsum[w - 1] : 0;
    int incl = xv + wpre;
    int carry = carry_s;
    if (i < N) {
      int excl = carry + incl - v;
      off[i]    = excl;
      cursor[i] = excl;
    }
    __syncthreads();
    if (tid == 1023) {
      carry_s = carry + incl;
      if (base + 1024 >= N) off[N] = carry + incl;
    }
    __syncthreads();
  }
}

// ======================================================================
// K5: CSR scatter (edges + self-loops)
// ======================================================================
__global__ __launch_bounds__(256) void scatter(
    const int* __restrict__ src, const int* __restrict__ dst,
    int* __restrict__ cursor, int* __restrict__ csr, int E, int N)
{
  int e = blockIdx.x * blockDim.x + threadIdx.x;
  int Et = E + N;
  if (e >= Et) return;
  int s, d;
  if (e < E) { s = src[e]; d = dst[e]; }
  else       { s = e - E;  d = s; }
  int p = atomicAdd(&cursor[d], 1);
  csr[p] = s;
}

// ======================================================================
// K6: per-node online-softmax + weighted aggregation. 1 wave per node.
// Single gather of (csr, bj) per edge per chunk; chunk-max via shuffles;
// online rescale of running sum and accumulator across chunks.
// Lane owns output channels {2*lane, 2*lane+1} (head myh = lane>>4).
// ======================================================================
__global__ __launch_bounds__(64) void gat_node(
    const float* __restrict__ xl, const float* __restrict__ bj,
    const float* __restrict__ bi, const int* __restrict__ off,
    const int* __restrict__ csr, const float* __restrict__ bias,
    float* __restrict__ out, int N)
{
  const int n    = blockIdx.x;
  const int lane = threadIdx.x;
  const int start = off[n];
  const int D     = off[n + 1] - start;

  __shared__ int   s_src[64];
  __shared__ float s_w[64][4];

  const int myh = lane >> 4;
  float2 acc = make_float2(0.f, 0.f);
  float m0 = -1e30f, m1 = -1e30f, m2 = -1e30f, m3 = -1e30f;
  float sp0 = 0.f, sp1 = 0.f, sp2 = 0.f, sp3 = 0.f;  // per-lane partial expsums

  const float4 biv = ((const float4*)bi)[n];
  const float2* xl2 = (const float2*)xl;

  for (int base = 0; base < D; base += 64) {
    const int cnt = min(64, D - base);
    const bool valid = lane < cnt;
    float a0 = -1e30f, a1 = -1e30f, a2 = -1e30f, a3 = -1e30f;
    if (valid) {
      int s = csr[start + base + lane];
      s_src[lane] = s;
      float4 bv = ((const float4*)bj)[s];
      a0 = bv.x + biv.x; a0 = a0 >= 0.f ? a0 : NEG * a0;
      a1 = bv.y + biv.y; a1 = a1 >= 0.f ? a1 : NEG * a1;
      a2 = bv.z + biv.z; a2 = a2 >= 0.f ? a2 : NEG * a2;
      a3 = bv.w + biv.w; a3 = a3 >= 0.f ? a3 : NEG * a3;
    }
    // chunk max per head across 64 lanes
    float c0 = a0, c1 = a1, c2 = a2, c3 = a3;
    #pragma unroll
    for (int mask = 1; mask < 64; mask <<= 1) {
      c0 = fmaxf(c0, __shfl_xor(c0, mask));
      c1 = fmaxf(c1, __shfl_xor(c1, mask));
      c2 = fmaxf(c2, __shfl_xor(c2, mask));
      c3 = fmaxf(c3, __shfl_xor(c3, mask));
    }
    // online rescale of running state
    float nm0 = fmaxf(m0, c0), nm1 = fmaxf(m1, c1);
    float nm2 = fmaxf(m2, c2), nm3 = fmaxf(m3, c3);
    float sc0 = __expf(m0 - nm0), sc1 = __expf(m1 - nm1);
    float sc2 = __expf(m2 - nm2), sc3 = __expf(m3 - nm3);
    m0 = nm0; m1 = nm1; m2 = nm2; m3 = nm3;
    sp0 *= sc0; sp1 *= sc1; sp2 *= sc2; sp3 *= sc3;
    float asc = (myh == 0) ? sc0 : (myh == 1) ? sc1 : (myh == 2) ? sc2 : sc3;
    acc.x *= asc; acc.y *= asc;
    // exp weights -> LDS (+ per-lane partial sums)
    if (valid) {
      float e0 = __expf(a0 - nm0), e1 = __expf(a1 - nm1);
      float e2 = __expf(a2 - nm2), e3 = __expf(a3 - nm3);
      sp0 += e0; sp1 += e1; sp2 += e2; sp3 += e3;
      s_w[lane][0] = e0; s_w[lane][1] = e1;
      s_w[lane][2] = e2; s_w[lane][3] = e3;
    }
    __syncthreads();
    // weighted aggregation: each edge reads one 512B row of xl per wave
    #pragma unroll 4
    for (int d = 0; d < cnt; ++d) {
      float w = s_w[d][myh];
      float2 v = xl2[(size_t)s_src[d] * 64 + lane];
      acc.x = fmaf(w, v.x, acc.x);
      acc.y = fmaf(w, v.y, acc.y);
    }
    __syncthreads();
  }

  // final expsum reduction per head
  #pragma unroll
  for (int mask = 1; mask < 64; mask <<= 1) {
    sp0 += __shfl_xor(sp0, mask);
    sp1 += __shfl_xor(sp1, mask);
    sp2 += __shfl_xor(sp2, mask);
    sp3 += __shfl_xor(sp3, mask);
  }
  float sum = (myh == 0) ? sp0 : (myh == 1) ? sp1 : (myh == 2) ? sp2 : sp3;
  float rs = 1.f / sum;
  const int c0i = 2 * lane;
  out[(size_t)n * 128 + c0i]     = fmaf(acc.x, rs, bias[c0i]);
  out[(size_t)n * 128 + c0i + 1] = fmaf(acc.y, rs, bias[c0i + 1]);
}

// ======================================================================
extern "C" void kernel_launch(void* const* d_in, const int* in_sizes, int n_in,
                              void* d_out, int out_size, void* d_ws, size_t ws_size,
                              hipStream_t stream) {
  const float* x      = (const float*)d_in[0];
  const float* W      = (const float*)d_in[1];
  const float* attn_j = (const float*)d_in[2];
  const float* attn_i = (const float*)d_in[3];
  const float* bias   = (const float*)d_in[4];
  const int*   eidx   = (const int*)d_in[5];

  const int N = in_sizes[0] / 128;
  const int E = in_sizes[5] / 2;
  const int Et = E + N;
  const int* src = eidx;
  const int* dst = eidx + E;
  float* out = (float*)d_out;

  // workspace carve (256B aligned)
  char* p = (char*)d_ws;
  auto alloc = [&](size_t bytes) -> char* {
    char* q = p;
    p += (bytes + 255) & ~(size_t)255;
    return q;
  };
  float* xl     = (float*)alloc((size_t)N * 128 * sizeof(float));
  float* aj     = (float*)alloc((size_t)N * 4 * sizeof(float));
  float* ai     = (float*)alloc((size_t)N * 4 * sizeof(float));
  float* bj     = (float*)alloc((size_t)N * 4 * sizeof(float));
  float* bi     = (float*)alloc((size_t)N * 4 * sizeof(float));
  int*   deg    = (int*)alloc((size_t)(N + 1) * sizeof(int));
  int*   off    = (int*)alloc((size_t)(N + 1) * sizeof(int));
  int*   cursor = (int*)alloc((size_t)N * sizeof(int));
  int*   csr    = (int*)alloc((size_t)Et * sizeof(int));

  // 1. GEMM + fused node scores
  gemm_node<<<(N + 63) / 64, 256, 0, stream>>>(x, W, attn_j, attn_i, xl, aj, ai, N);
  // 2. double-gather resolution + deg init
  node_prep<<<(N + 255) / 256, 256, 0, stream>>>(aj, ai, src, dst, bj, bi, deg, N);
  // 3-5. CSR build
  hist<<<(E + 255) / 256, 256, 0, stream>>>(dst, deg, E);
  scan_kernel<<<1, 1024, 0, stream>>>(deg, off, cursor, N);
  scatter<<<(Et + 255) / 256, 256, 0, stream>>>(src, dst, cursor, csr, E, N);
  // 6. online softmax + aggregation
  gat_node<<<N, 64, 0, stream>>>(xl, bj, bi, off, csr, bias, out, N);
}

// Round 8
// 292.678 us; speedup vs baseline: 1.6266x; 1.6266x over previous
//
#include <hip/hip_runtime.h>

#define NEG 0.2f
// CSR build via counting sort: 128 nodes per bucket (requires N <= 65536 so
// src ids pack into 16 bits of a u32 alongside the 7-bit local dst).
#define BKT_SHIFT 7
#define BKT_NODES 128
#define MAXB 512        // LDS histogram capacity (B = ceil(N/128) must be <= 512)
#define LCAP 6144       // per-bucket LDS CSR segment capacity (avg ~4220, 30-sigma margin)

// ======================================================================
// K1: xl = x @ W^T  (fp32, K-tiled LDS GEMM), fused per-node scores
//     aj[n,h] = sum_c xl[n,h,c]*attn_j[h,c],  ai likewise.
// ======================================================================
__global__ __launch_bounds__(256, 2) void gemm_node(
    const float* __restrict__ x, const float* __restrict__ W,
    const float* __restrict__ attn_j, const float* __restrict__ attn_i,
    float* __restrict__ xl, float* __restrict__ aj, float* __restrict__ ai,
    int N)
{
  __shared__ float wt[64][132];   // wt[k][m] = W[m][kt+k]
  __shared__ float xs[64][68];    // xs[r][k] = x[r0+r][kt+k]
  const int tid = threadIdx.x;
  const int r0 = blockIdx.x * 64;
  const int tc = tid & 15;
  const int tr = tid >> 4;

  float acc[4][8];
  #pragma unroll
  for (int i = 0; i < 4; ++i)
    #pragma unroll
    for (int j = 0; j < 8; ++j) acc[i][j] = 0.f;

  for (int kt = 0; kt < 128; kt += 64) {
    __syncthreads();
    #pragma unroll
    for (int it = 0; it < 8; ++it) {
      int id = tid + 256 * it;          // 0..2047
      int m  = id >> 4;                 // 0..127
      int k4 = id & 15;                 // 0..15
      float4 w4 = ((const float4*)W)[(size_t)m * 32 + (kt >> 2) + k4];
      wt[k4 * 4 + 0][m] = w4.x;
      wt[k4 * 4 + 1][m] = w4.y;
      wt[k4 * 4 + 2][m] = w4.z;
      wt[k4 * 4 + 3][m] = w4.w;
    }
    #pragma unroll
    for (int it = 0; it < 4; ++it) {
      int id = tid + 256 * it;          // 0..1023
      int r  = id >> 4;
      int k4 = id & 15;
      int row = r0 + r;
      float4 v = make_float4(0.f, 0.f, 0.f, 0.f);
      if (row < N) v = ((const float4*)x)[(size_t)row * 32 + (kt >> 2) + k4];
      *(float4*)&xs[r][k4 * 4] = v;
    }
    __syncthreads();

    #pragma unroll 2
    for (int k = 0; k < 64; ++k) {
      float4 wa = *(const float4*)&wt[k][tc * 4];        // cols 4tc..+3
      float4 wb = *(const float4*)&wt[k][64 + tc * 4];   // cols 64+4tc..+3
      #pragma unroll
      for (int i = 0; i < 4; ++i) {
        float xv = xs[tr * 4 + i][k];
        acc[i][0] = fmaf(xv, wa.x, acc[i][0]);
        acc[i][1] = fmaf(xv, wa.y, acc[i][1]);
        acc[i][2] = fmaf(xv, wa.z, acc[i][2]);
        acc[i][3] = fmaf(xv, wa.w, acc[i][3]);
        acc[i][4] = fmaf(xv, wb.x, acc[i][4]);
        acc[i][5] = fmaf(xv, wb.y, acc[i][5]);
        acc[i][6] = fmaf(xv, wb.z, acc[i][6]);
        acc[i][7] = fmaf(xv, wb.w, acc[i][7]);
      }
    }
  }

  const int h0 = tc >> 3;
  const int h1 = 2 + h0;
  const int cb = 4 * (tc & 7);
  #pragma unroll
  for (int i = 0; i < 4; ++i) {
    int row = r0 + tr * 4 + i;
    float pj0 = 0.f, pi0 = 0.f, pj1 = 0.f, pi1 = 0.f;
    #pragma unroll
    for (int j = 0; j < 4; ++j) {
      pj0 = fmaf(acc[i][j],     attn_j[h0 * 32 + cb + j], pj0);
      pi0 = fmaf(acc[i][j],     attn_i[h0 * 32 + cb + j], pi0);
      pj1 = fmaf(acc[i][4 + j], attn_j[h1 * 32 + cb + j], pj1);
      pi1 = fmaf(acc[i][4 + j], attn_i[h1 * 32 + cb + j], pi1);
    }
    #pragma unroll
    for (int mask = 1; mask < 8; mask <<= 1) {
      pj0 += __shfl_xor(pj0, mask);
      pi0 += __shfl_xor(pi0, mask);
      pj1 += __shfl_xor(pj1, mask);
      pi1 += __shfl_xor(pi1, mask);
    }
    if (row < N) {
      float4 o0 = make_float4(acc[i][0], acc[i][1], acc[i][2], acc[i][3]);
      float4 o1 = make_float4(acc[i][4], acc[i][5], acc[i][6], acc[i][7]);
      ((float4*)xl)[(size_t)row * 32 + tc]      = o0;
      ((float4*)xl)[(size_t)row * 32 + 16 + tc] = o1;
      if ((tid & 7) == 0) {
        aj[row * 4 + h0] = pj0;
        ai[row * 4 + h0] = pi0;
        aj[row * 4 + h1] = pj1;
        ai[row * 4 + h1] = pi1;
      }
    }
  }
}

// ======================================================================
// K2: double-gather resolution (bj[n]=aj[src[n]], bi[n]=ai[dst[n]])
//     + zero the bucket histogram for the CSR sort.
// ======================================================================
__global__ __launch_bounds__(256) void node_prep(
    const float* __restrict__ aj, const float* __restrict__ ai,
    const int* __restrict__ src, const int* __restrict__ dst,
    float* __restrict__ bj, float* __restrict__ bi,
    int* __restrict__ gcnt, int B, int N)
{
  int n = blockIdx.x * blockDim.x + threadIdx.x;
  if (n <= B) gcnt[n] = 0;
  if (n >= N) return;
  ((float4*)bj)[n] = ((const float4*)aj)[src[n]];
  ((float4*)bi)[n] = ((const float4*)ai)[dst[n]];
}

// ======================================================================
// K3: bucket histogram (LDS-aggregated; ~B global atomics per block)
// ======================================================================
__global__ __launch_bounds__(256) void bucket_hist(
    const int* __restrict__ dst, int* __restrict__ gcnt, int E)
{
  __shared__ int lhist[MAXB];
  const int tid = threadIdx.x;
  for (int i = tid; i < MAXB; i += 256) lhist[i] = 0;
  __syncthreads();
  const int base = blockIdx.x * 4096;
  #pragma unroll
  for (int k = 0; k < 16; ++k) {
    int e = base + tid + 256 * k;
    if (e < E) atomicAdd(&lhist[dst[e] >> BKT_SHIFT], 1);
  }
  __syncthreads();
  for (int i = tid; i < MAXB; i += 256)
    if (lhist[i]) atomicAdd(&gcnt[i], lhist[i]);
}

// ======================================================================
// K4: scan of bucket counts -> bin_off (exclusive) + cursor copy
// ======================================================================
__global__ __launch_bounds__(512) void bucket_scan(
    const int* __restrict__ gcnt, int* __restrict__ bin_off,
    int* __restrict__ bcur, int B)
{
  __shared__ int tmp[512];
  const int tid = threadIdx.x;
  int v = (tid < B) ? gcnt[tid] : 0;
  tmp[tid] = v;
  __syncthreads();
  #pragma unroll
  for (int d = 1; d < 512; d <<= 1) {
    int y = (tid >= d) ? tmp[tid - d] : 0;
    __syncthreads();
    tmp[tid] += y;
    __syncthreads();
  }
  if (tid < B) {
    int ex = tmp[tid] - v;
    bin_off[tid] = ex;
    bcur[tid] = ex;
  }
  if (tid == 0) bin_off[B] = tmp[511];
}

// ======================================================================
// K5: scatter edges into bucket segments (packed u32: src | dstLocal<<16).
// Per-block LDS ranks + one global atomic per touched bucket -> writes are
// contiguous runs inside each bucket segment (L2-mergeable).
// ======================================================================
__global__ __launch_bounds__(256) void bucket_scatter(
    const int* __restrict__ src, const int* __restrict__ dst,
    int* __restrict__ bcur, unsigned* __restrict__ bins, int E)
{
  __shared__ int lhist[MAXB];
  __shared__ int lbase[MAXB];
  const int tid = threadIdx.x;
  for (int i = tid; i < MAXB; i += 256) lhist[i] = 0;
  __syncthreads();
  const int base = blockIdx.x * 4096;
  int es[16], eb[16], edl[16];
  #pragma unroll
  for (int k = 0; k < 16; ++k) {
    int e = base + tid + 256 * k;
    if (e < E) {
      es[k] = src[e];
      int d = dst[e];
      eb[k]  = d >> BKT_SHIFT;
      edl[k] = d & (BKT_NODES - 1);
      atomicAdd(&lhist[eb[k]], 1);
    } else eb[k] = -1;
  }
  __syncthreads();
  for (int i = tid; i < MAXB; i += 256) {
    int c = lhist[i];
    lbase[i] = c ? atomicAdd(&bcur[i], c) : 0;
  }
  __syncthreads();
  for (int i = tid; i < MAXB; i += 256) lhist[i] = 0;
  __syncthreads();
  #pragma unroll
  for (int k = 0; k < 16; ++k) {
    if (eb[k] >= 0) {
      int r = atomicAdd(&lhist[eb[k]], 1);
      bins[lbase[eb[k]] + r] = (unsigned)es[k] | ((unsigned)edl[k] << 16);
    }
  }
}

// ======================================================================
// K6: per-bucket CSR build in LDS; coalesced csr/off writes.
// Self-loop inserted at slot 0 of each node's segment.
// Global edge base for bucket b = bin_off[b] + n0 (preceding self-loops).
// ======================================================================
__global__ __launch_bounds__(256) void bucket_csr(
    const unsigned* __restrict__ bins, const int* __restrict__ bin_off,
    int* __restrict__ off, int* __restrict__ csr, int N, int B, int Et)
{
  __shared__ int ldeg[BKT_NODES];
  __shared__ int lsc[BKT_NODES];
  __shared__ int lcur[BKT_NODES];
  __shared__ int lcsr[LCAP];
  const int b = blockIdx.x;
  const int tid = threadIdx.x;
  const int n0 = b << BKT_SHIFT;
  const int nn = min(BKT_NODES, N - n0);
  const int e0 = bin_off[b];
  const int cnt = bin_off[b + 1] - e0;
  const int edgeBase = e0 + n0;
  const int tot = cnt + nn;
  const bool inlds = (tot <= LCAP);

  if (tid < BKT_NODES) ldeg[tid] = (tid < nn) ? 1 : 0;  // 1 = self-loop
  __syncthreads();
  for (int i = tid; i < cnt; i += 256)
    atomicAdd(&ldeg[bins[e0 + i] >> 16], 1);
  __syncthreads();
  if (tid < BKT_NODES) lsc[tid] = ldeg[tid];
  __syncthreads();
  #pragma unroll
  for (int d = 1; d < BKT_NODES; d <<= 1) {
    int y = 0;
    if (tid < BKT_NODES && tid >= d) y = lsc[tid - d];
    __syncthreads();
    if (tid < BKT_NODES) lsc[tid] += y;
    __syncthreads();
  }
  // lsc inclusive -> exclusive ex = lsc - ldeg
  if (tid < nn) {
    int ex = lsc[tid] - ldeg[tid];
    lcur[tid] = ex + 1;                 // edges start after self-loop slot
    off[n0 + tid] = edgeBase + ex;
    if (inlds) lcsr[ex] = n0 + tid;
    else       csr[edgeBase + ex] = n0 + tid;
  }
  __syncthreads();
  if (inlds) {
    for (int i = tid; i < cnt; i += 256) {
      unsigned p = bins[e0 + i];
      int r = atomicAdd(&lcur[p >> 16], 1);
      lcsr[r] = (int)(p & 0xFFFFu);
    }
    __syncthreads();
    for (int i = tid; i < tot; i += 256) csr[edgeBase + i] = lcsr[i];
  } else {  // statistical never-path; correctness fallback
    for (int i = tid; i < cnt; i += 256) {
      unsigned p = bins[e0 + i];
      int r = atomicAdd(&lcur[p >> 16], 1);
      csr[edgeBase + r] = (int)(p & 0xFFFFu);
    }
  }
  if (b == B - 1 && tid == 0) off[N] = Et;
}

// ======================================================================
// K7: online-softmax + weighted aggregation. 256 threads = 4 independent
// waves, one NODE per wave. No block barriers: all cross-lane traffic is
// intra-wave (wave64 lockstep); LDS weight broadcast ordered by explicit
// s_waitcnt lgkmcnt(0). Lane owns channels {2*lane,2*lane+1}, head=lane>>4.
// ======================================================================
__global__ __launch_bounds__(256) void gat_node(
    const float* __restrict__ xl, const float* __restrict__ bj,
    const float* __restrict__ bi, const int* __restrict__ off,
    const int* __restrict__ csr, const float* __restrict__ bias,
    float* __restrict__ out, int N)
{
  const int tid  = threadIdx.x;
  const int wv   = tid >> 6;
  const int lane = tid & 63;
  const int n    = blockIdx.x * 4 + wv;
  if (n >= N) return;

  __shared__ float s_w[4][64][4];
  float* sw = &s_w[wv][0][0];

  const int start = off[n];
  const int D     = off[n + 1] - start;
  const int myh   = lane >> 4;

  float2 acc = make_float2(0.f, 0.f);
  float m0 = -1e30f, m1 = -1e30f, m2 = -1e30f, m3 = -1e30f;
  float sp0 = 0.f, sp1 = 0.f, sp2 = 0.f, sp3 = 0.f;

  const float4 biv = ((const float4*)bi)[n];
  const float2* xl2 = (const float2*)xl;

  for (int base = 0; base < D; base += 64) {
    const int cnt = min(64, D - base);
    const bool valid = lane < cnt;
    int s_reg = 0;
    float a0 = -1e30f, a1 = -1e30f, a2 = -1e30f, a3 = -1e30f;
    if (valid) {
      s_reg = csr[start + base + lane];
      float4 bv = ((const float4*)bj)[s_reg];
      a0 = bv.x + biv.x; a0 = a0 >= 0.f ? a0 : NEG * a0;
      a1 = bv.y + biv.y; a1 = a1 >= 0.f ? a1 : NEG * a1;
      a2 = bv.z + biv.z; a2 = a2 >= 0.f ? a2 : NEG * a2;
      a3 = bv.w + biv.w; a3 = a3 >= 0.f ? a3 : NEG * a3;
    }
    // chunk max per head across 64 lanes
    float c0 = a0, c1 = a1, c2 = a2, c3 = a3;
    #pragma unroll
    for (int mask = 1; mask < 64; mask <<= 1) {
      c0 = fmaxf(c0, __shfl_xor(c0, mask));
      c1 = fmaxf(c1, __shfl_xor(c1, mask));
      c2 = fmaxf(c2, __shfl_xor(c2, mask));
      c3 = fmaxf(c3, __shfl_xor(c3, mask));
    }
    // online rescale of running state
    float nm0 = fmaxf(m0, c0), nm1 = fmaxf(m1, c1);
    float nm2 = fmaxf(m2, c2), nm3 = fmaxf(m3, c3);
    float sc0 = __expf(m0 - nm0), sc1 = __expf(m1 - nm1);
    float sc2 = __expf(m2 - nm2), sc3 = __expf(m3 - nm3);
    m0 = nm0; m1 = nm1; m2 = nm2; m3 = nm3;
    sp0 *= sc0; sp1 *= sc1; sp2 *= sc2; sp3 *= sc3;
    float asc = (myh == 0) ? sc0 : (myh == 1) ? sc1 : (myh == 2) ? sc2 : sc3;
    acc.x *= asc; acc.y *= asc;
    // wait for prior chunk's sw reads before overwriting (WAR; rare D>64 path)
    asm volatile("s_waitcnt lgkmcnt(0)" ::: "memory");
    if (valid) {
      float e0v = __expf(a0 - nm0), e1v = __expf(a1 - nm1);
      float e2v = __expf(a2 - nm2), e3v = __expf(a3 - nm3);
      sp0 += e0v; sp1 += e1v; sp2 += e2v; sp3 += e3v;
      sw[lane * 4 + 0] = e0v; sw[lane * 4 + 1] = e1v;
      sw[lane * 4 + 2] = e2v; sw[lane * 4 + 3] = e3v;
    }
    // make LDS writes visible to all lanes of this wave (lockstep, no barrier)
    asm volatile("s_waitcnt lgkmcnt(0)" ::: "memory");
    // weighted aggregation: each edge = one 512B wave-coalesced row of xl
    #pragma unroll 8
    for (int d = 0; d < cnt; ++d) {
      float w = sw[d * 4 + myh];
      int sd = __shfl(s_reg, d);
      float2 v = xl2[(size_t)sd * 64 + lane];
      acc.x = fmaf(w, v.x, acc.x);
      acc.y = fmaf(w, v.y, acc.y);
    }
  }

  // final expsum reduction per head
  #pragma unroll
  for (int mask = 1; mask < 64; mask <<= 1) {
    sp0 += __shfl_xor(sp0, mask);
    sp1 += __shfl_xor(sp1, mask);
    sp2 += __shfl_xor(sp2, mask);
    sp3 += __shfl_xor(sp3, mask);
  }
  float sum = (myh == 0) ? sp0 : (myh == 1) ? sp1 : (myh == 2) ? sp2 : sp3;
  float rs = 1.f / sum;
  const int c0i = 2 * lane;
  out[(size_t)n * 128 + c0i]     = fmaf(acc.x, rs, bias[c0i]);
  out[(size_t)n * 128 + c0i + 1] = fmaf(acc.y, rs, bias[c0i + 1]);
}

// ======================================================================
extern "C" void kernel_launch(void* const* d_in, const int* in_sizes, int n_in,
                              void* d_out, int out_size, void* d_ws, size_t ws_size,
                              hipStream_t stream) {
  const float* x      = (const float*)d_in[0];
  const float* W      = (const float*)d_in[1];
  const float* attn_j = (const float*)d_in[2];
  const float* attn_i = (const float*)d_in[3];
  const float* bias   = (const float*)d_in[4];
  const int*   eidx   = (const int*)d_in[5];

  const int N = in_sizes[0] / 128;
  const int E = in_sizes[5] / 2;
  const int Et = E + N;
  const int B = (N + BKT_NODES - 1) / BKT_NODES;   // 391 for N=50000
  const int* src = eidx;
  const int* dst = eidx + E;
  float* out = (float*)d_out;

  // workspace carve (256B aligned)
  char* p = (char*)d_ws;
  auto alloc = [&](size_t bytes) -> char* {
    char* q = p;
    p += (bytes + 255) & ~(size_t)255;
    return q;
  };
  float*    xl      = (float*)alloc((size_t)N * 128 * sizeof(float));
  float*    aj      = (float*)alloc((size_t)N * 4 * sizeof(float));
  float*    ai      = (float*)alloc((size_t)N * 4 * sizeof(float));
  float*    bj      = (float*)alloc((size_t)N * 4 * sizeof(float));
  float*    bi      = (float*)alloc((size_t)N * 4 * sizeof(float));
  int*      gcnt    = (int*)alloc((size_t)(B + 1) * sizeof(int));
  int*      bin_off = (int*)alloc((size_t)(B + 1) * sizeof(int));
  int*      bcur    = (int*)alloc((size_t)B * sizeof(int));
  int*      off     = (int*)alloc((size_t)(N + 1) * sizeof(int));
  int*      csr     = (int*)alloc((size_t)Et * sizeof(int));
  unsigned* bins    = (unsigned*)alloc((size_t)E * sizeof(unsigned));

  const int ebpb = 4096;  // edges per block in hist/scatter
  // 1. GEMM + fused node scores
  gemm_node<<<(N + 63) / 64, 256, 0, stream>>>(x, W, attn_j, attn_i, xl, aj, ai, N);
  // 2. double-gather resolution + gcnt zero
  node_prep<<<(N + 255) / 256, 256, 0, stream>>>(aj, ai, src, dst, bj, bi, gcnt, B, N);
  // 3-6. CSR build via bucket counting sort
  bucket_hist<<<(E + ebpb - 1) / ebpb, 256, 0, stream>>>(dst, gcnt, E);
  bucket_scan<<<1, 512, 0, stream>>>(gcnt, bin_off, bcur, B);
  bucket_scatter<<<(E + ebpb - 1) / ebpb, 256, 0, stream>>>(src, dst, bcur, bins, E);
  bucket_csr<<<B, 256, 0, stream>>>(bins, bin_off, off, csr, N, B, Et);
  // 7. online softmax + aggregation (4 nodes per 256-thr block, barrier-free)
  gat_node<<<(N + 3) / 4, 256, 0, stream>>>(xl, bj, bi, off, csr, bias, out, N);
}

// Round 13
// 282.825 us; speedup vs baseline: 1.6832x; 1.0348x over previous
//
#include <hip/hip_runtime.h>

#define NEG 0.2f
// CSR build via counting sort: 128 nodes per bucket (requires N <= 65536 so
// src ids pack into 16 bits of a u32 alongside the 7-bit local dst).
#define BKT_SHIFT 7
#define BKT_NODES 128
#define MAXB 512        // LDS histogram capacity (B = ceil(N/128) must be <= 512)
#define LCAP 6144       // per-bucket LDS CSR segment capacity (avg ~4220, 30-sigma margin)

// ======================================================================
// K1: xl = x @ W^T  (fp32, K-tiled LDS GEMM), fused per-node scores
//     aj[n,h] = sum_c xl[n,h,c]*attn_j[h,c],  ai likewise.
// ======================================================================
__global__ __launch_bounds__(256, 2) void gemm_node(
    const float* __restrict__ x, const float* __restrict__ W,
    const float* __restrict__ attn_j, const float* __restrict__ attn_i,
    float* __restrict__ xl, float* __restrict__ aj, float* __restrict__ ai,
    int N)
{
  __shared__ float wt[64][132];   // wt[k][m] = W[m][kt+k]
  __shared__ float xs[64][68];    // xs[r][k] = x[r0+r][kt+k]
  const int tid = threadIdx.x;
  const int r0 = blockIdx.x * 64;
  const int tc = tid & 15;
  const int tr = tid >> 4;

  float acc[4][8];
  #pragma unroll
  for (int i = 0; i < 4; ++i)
    #pragma unroll
    for (int j = 0; j < 8; ++j) acc[i][j] = 0.f;

  for (int kt = 0; kt < 128; kt += 64) {
    __syncthreads();
    #pragma unroll
    for (int it = 0; it < 8; ++it) {
      int id = tid + 256 * it;          // 0..2047
      int m  = id >> 4;                 // 0..127
      int k4 = id & 15;                 // 0..15
      float4 w4 = ((const float4*)W)[(size_t)m * 32 + (kt >> 2) + k4];
      wt[k4 * 4 + 0][m] = w4.x;
      wt[k4 * 4 + 1][m] = w4.y;
      wt[k4 * 4 + 2][m] = w4.z;
      wt[k4 * 4 + 3][m] = w4.w;
    }
    #pragma unroll
    for (int it = 0; it < 4; ++it) {
      int id = tid + 256 * it;          // 0..1023
      int r  = id >> 4;
      int k4 = id & 15;
      int row = r0 + r;
      float4 v = make_float4(0.f, 0.f, 0.f, 0.f);
      if (row < N) v = ((const float4*)x)[(size_t)row * 32 + (kt >> 2) + k4];
      *(float4*)&xs[r][k4 * 4] = v;
    }
    __syncthreads();

    #pragma unroll 2
    for (int k = 0; k < 64; ++k) {
      float4 wa = *(const float4*)&wt[k][tc * 4];        // cols 4tc..+3
      float4 wb = *(const float4*)&wt[k][64 + tc * 4];   // cols 64+4tc..+3
      #pragma unroll
      for (int i = 0; i < 4; ++i) {
        float xv = xs[tr * 4 + i][k];
        acc[i][0] = fmaf(xv, wa.x, acc[i][0]);
        acc[i][1] = fmaf(xv, wa.y, acc[i][1]);
        acc[i][2] = fmaf(xv, wa.z, acc[i][2]);
        acc[i][3] = fmaf(xv, wa.w, acc[i][3]);
        acc[i][4] = fmaf(xv, wb.x, acc[i][4]);
        acc[i][5] = fmaf(xv, wb.y, acc[i][5]);
        acc[i][6] = fmaf(xv, wb.z, acc[i][6]);
        acc[i][7] = fmaf(xv, wb.w, acc[i][7]);
      }
    }
  }

  const int h0 = tc >> 3;
  const int h1 = 2 + h0;
  const int cb = 4 * (tc & 7);
  #pragma unroll
  for (int i = 0; i < 4; ++i) {
    int row = r0 + tr * 4 + i;
    float pj0 = 0.f, pi0 = 0.f, pj1 = 0.f, pi1 = 0.f;
    #pragma unroll
    for (int j = 0; j < 4; ++j) {
      pj0 = fmaf(acc[i][j],     attn_j[h0 * 32 + cb + j], pj0);
      pi0 = fmaf(acc[i][j],     attn_i[h0 * 32 + cb + j], pi0);
      pj1 = fmaf(acc[i][4 + j], attn_j[h1 * 32 + cb + j], pj1);
      pi1 = fmaf(acc[i][4 + j], attn_i[h1 * 32 + cb + j], pi1);
    }
    #pragma unroll
    for (int mask = 1; mask < 8; mask <<= 1) {
      pj0 += __shfl_xor(pj0, mask);
      pi0 += __shfl_xor(pi0, mask);
      pj1 += __shfl_xor(pj1, mask);
      pi1 += __shfl_xor(pi1, mask);
    }
    if (row < N) {
      float4 o0 = make_float4(acc[i][0], acc[i][1], acc[i][2], acc[i][3]);
      float4 o1 = make_float4(acc[i][4], acc[i][5], acc[i][6], acc[i][7]);
      ((float4*)xl)[(size_t)row * 32 + tc]      = o0;
      ((float4*)xl)[(size_t)row * 32 + 16 + tc] = o1;
      if ((tid & 7) == 0) {
        aj[row * 4 + h0] = pj0;
        ai[row * 4 + h0] = pi0;
        aj[row * 4 + h1] = pj1;
        ai[row * 4 + h1] = pi1;
      }
    }
  }
}

// ======================================================================
// K2: double-gather resolution (bj[n]=aj[src[n]], bi[n]=ai[dst[n]])
//     + zero the bucket histogram for the CSR sort.
// ======================================================================
__global__ __launch_bounds__(256) void node_prep(
    const float* __restrict__ aj, const float* __restrict__ ai,
    const int* __restrict__ src, const int* __restrict__ dst,
    float* __restrict__ bj, float* __restrict__ bi,
    int* __restrict__ gcnt, int B, int N)
{
  int n = blockIdx.x * blockDim.x + threadIdx.x;
  if (n <= B) gcnt[n] = 0;
  if (n >= N) return;
  ((float4*)bj)[n] = ((const float4*)aj)[src[n]];
  ((float4*)bi)[n] = ((const float4*)ai)[dst[n]];
}

// ======================================================================
// K3: bucket histogram (LDS-aggregated; ~B global atomics per block)
// ======================================================================
__global__ __launch_bounds__(256) void bucket_hist(
    const int* __restrict__ dst, int* __restrict__ gcnt, int E)
{
  __shared__ int lhist[MAXB];
  const int tid = threadIdx.x;
  for (int i = tid; i < MAXB; i += 256) lhist[i] = 0;
  __syncthreads();
  const int base = blockIdx.x * 4096;
  #pragma unroll
  for (int k = 0; k < 16; ++k) {
    int e = base + tid + 256 * k;
    if (e < E) atomicAdd(&lhist[dst[e] >> BKT_SHIFT], 1);
  }
  __syncthreads();
  for (int i = tid; i < MAXB; i += 256)
    if (lhist[i]) atomicAdd(&gcnt[i], lhist[i]);
}

// ======================================================================
// K4: scan of bucket counts -> bin_off (exclusive) + cursor copy
// ======================================================================
__global__ __launch_bounds__(512) void bucket_scan(
    const int* __restrict__ gcnt, int* __restrict__ bin_off,
    int* __restrict__ bcur, int B)
{
  __shared__ int tmp[512];
  const int tid = threadIdx.x;
  int v = (tid < B) ? gcnt[tid] : 0;
  tmp[tid] = v;
  __syncthreads();
  #pragma unroll
  for (int d = 1; d < 512; d <<= 1) {
    int y = (tid >= d) ? tmp[tid - d] : 0;
    __syncthreads();
    tmp[tid] += y;
    __syncthreads();
  }
  if (tid < B) {
    int ex = tmp[tid] - v;
    bin_off[tid] = ex;
    bcur[tid] = ex;
  }
  if (tid == 0) bin_off[B] = tmp[511];
}

// ======================================================================
// K5: scatter edges into bucket segments (packed u32: src | dstLocal<<16).
// Per-block LDS ranks + one global atomic per touched bucket -> writes are
// contiguous runs inside each bucket segment (L2-mergeable).
// ======================================================================
__global__ __launch_bounds__(256) void bucket_scatter(
    const int* __restrict__ src, const int* __restrict__ dst,
    int* __restrict__ bcur, unsigned* __restrict__ bins, int E)
{
  __shared__ int lhist[MAXB];
  __shared__ int lbase[MAXB];
  const int tid = threadIdx.x;
  for (int i = tid; i < MAXB; i += 256) lhist[i] = 0;
  __syncthreads();
  const int base = blockIdx.x * 4096;
  int es[16], eb[16], edl[16];
  #pragma unroll
  for (int k = 0; k < 16; ++k) {
    int e = base + tid + 256 * k;
    if (e < E) {
      es[k] = src[e];
      int d = dst[e];
      eb[k]  = d >> BKT_SHIFT;
      edl[k] = d & (BKT_NODES - 1);
      atomicAdd(&lhist[eb[k]], 1);
    } else eb[k] = -1;
  }
  __syncthreads();
  for (int i = tid; i < MAXB; i += 256) {
    int c = lhist[i];
    lbase[i] = c ? atomicAdd(&bcur[i], c) : 0;
  }
  __syncthreads();
  for (int i = tid; i < MAXB; i += 256) lhist[i] = 0;
  __syncthreads();
  #pragma unroll
  for (int k = 0; k < 16; ++k) {
    if (eb[k] >= 0) {
      int r = atomicAdd(&lhist[eb[k]], 1);
      bins[lbase[eb[k]] + r] = (unsigned)es[k] | ((unsigned)edl[k] << 16);
    }
  }
}

// ======================================================================
// K6: per-bucket CSR build in LDS; coalesced csr/off writes.
// Self-loop inserted at slot 0 of each node's segment.
// Global edge base for bucket b = bin_off[b] + n0 (preceding self-loops).
// ======================================================================
__global__ __launch_bounds__(256) void bucket_csr(
    const unsigned* __restrict__ bins, const int* __restrict__ bin_off,
    int* __restrict__ off, int* __restrict__ csr, int N, int B, int Et)
{
  __shared__ int ldeg[BKT_NODES];
  __shared__ int lsc[BKT_NODES];
  __shared__ int lcur[BKT_NODES];
  __shared__ int lcsr[LCAP];
  const int b = blockIdx.x;
  const int tid = threadIdx.x;
  const int n0 = b << BKT_SHIFT;
  const int nn = min(BKT_NODES, N - n0);
  const int e0 = bin_off[b];
  const int cnt = bin_off[b + 1] - e0;
  const int edgeBase = e0 + n0;
  const int tot = cnt + nn;
  const bool inlds = (tot <= LCAP);

  if (tid < BKT_NODES) ldeg[tid] = (tid < nn) ? 1 : 0;  // 1 = self-loop
  __syncthreads();
  for (int i = tid; i < cnt; i += 256)
    atomicAdd(&ldeg[bins[e0 + i] >> 16], 1);
  __syncthreads();
  if (tid < BKT_NODES) lsc[tid] = ldeg[tid];
  __syncthreads();
  #pragma unroll
  for (int d = 1; d < BKT_NODES; d <<= 1) {
    int y = 0;
    if (tid < BKT_NODES && tid >= d) y = lsc[tid - d];
    __syncthreads();
    if (tid < BKT_NODES) lsc[tid] += y;
    __syncthreads();
  }
  // lsc inclusive -> exclusive ex = lsc - ldeg
  if (tid < nn) {
    int ex = lsc[tid] - ldeg[tid];
    lcur[tid] = ex + 1;                 // edges start after self-loop slot
    off[n0 + tid] = edgeBase + ex;
    if (inlds) lcsr[ex] = n0 + tid;
    else       csr[edgeBase + ex] = n0 + tid;
  }
  __syncthreads();
  if (inlds) {
    for (int i = tid; i < cnt; i += 256) {
      unsigned p = bins[e0 + i];
      int r = atomicAdd(&lcur[p >> 16], 1);
      lcsr[r] = (int)(p & 0xFFFFu);
    }
    __syncthreads();
    for (int i = tid; i < tot; i += 256) csr[edgeBase + i] = lcsr[i];
  } else {  // statistical never-path; correctness fallback
    for (int i = tid; i < cnt; i += 256) {
      unsigned p = bins[e0 + i];
      int r = atomicAdd(&lcur[p >> 16], 1);
      csr[edgeBase + r] = (int)(p & 0xFFFFu);
    }
  }
  if (b == B - 1 && tid == 0) off[N] = Et;
}

// ======================================================================
// K7: online-softmax + weighted aggregation. 256 threads = 4 independent
// waves, one NODE per wave; barrier-free (intra-wave lockstep + explicit
// s_waitcnt lgkmcnt(0) ordering the LDS weight broadcast).
// Aggregation processes TWO edges/iteration: lanes 0-31 = even edge,
// lanes 32-63 = odd edge; each lane owns 4 fixed channels (float4, 16B).
// Wave moves 1KB (2 xl rows) per iteration; cross-half combine at end.
// ======================================================================
__global__ __launch_bounds__(256) void gat_node(
    const float* __restrict__ xl, const float* __restrict__ bj,
    const float* __restrict__ bi, const int* __restrict__ off,
    const int* __restrict__ csr, const float* __restrict__ bias,
    float* __restrict__ out, int N)
{
  const int tid  = threadIdx.x;
  const int wv   = tid >> 6;
  const int lane = tid & 63;
  const int n    = blockIdx.x * 4 + wv;
  if (n >= N) return;

  __shared__ float s_w[4][64][4];
  float* sw = &s_w[wv][0][0];

  const int start = off[n];
  const int D     = off[n + 1] - start;
  const int half  = lane >> 5;        // which edge of the pair this lane serves
  const int cl    = lane & 31;        // channel group: channels 4cl..4cl+3
  const int hagg  = cl >> 3;          // head of those channels

  float4 acc = make_float4(0.f, 0.f, 0.f, 0.f);
  float m0 = -1e30f, m1 = -1e30f, m2 = -1e30f, m3 = -1e30f;
  float sp0 = 0.f, sp1 = 0.f, sp2 = 0.f, sp3 = 0.f;

  const float4 biv = ((const float4*)bi)[n];
  const float4* xl4 = (const float4*)xl;

  for (int base = 0; base < D; base += 64) {
    const int cnt = min(64, D - base);
    const bool valid = lane < cnt;
    int s_reg = 0;
    float a0 = -1e30f, a1 = -1e30f, a2 = -1e30f, a3 = -1e30f;
    if (valid) {
      s_reg = csr[start + base + lane];
      float4 bv = ((const float4*)bj)[s_reg];
      a0 = bv.x + biv.x; a0 = a0 >= 0.f ? a0 : NEG * a0;
      a1 = bv.y + biv.y; a1 = a1 >= 0.f ? a1 : NEG * a1;
      a2 = bv.z + biv.z; a2 = a2 >= 0.f ? a2 : NEG * a2;
      a3 = bv.w + biv.w; a3 = a3 >= 0.f ? a3 : NEG * a3;
    }
    // chunk max per head across 64 lanes
    float c0 = a0, c1 = a1, c2 = a2, c3 = a3;
    #pragma unroll
    for (int mask = 1; mask < 64; mask <<= 1) {
      c0 = fmaxf(c0, __shfl_xor(c0, mask));
      c1 = fmaxf(c1, __shfl_xor(c1, mask));
      c2 = fmaxf(c2, __shfl_xor(c2, mask));
      c3 = fmaxf(c3, __shfl_xor(c3, mask));
    }
    // online rescale of running state
    float nm0 = fmaxf(m0, c0), nm1 = fmaxf(m1, c1);
    float nm2 = fmaxf(m2, c2), nm3 = fmaxf(m3, c3);
    float sc0 = __expf(m0 - nm0), sc1 = __expf(m1 - nm1);
    float sc2 = __expf(m2 - nm2), sc3 = __expf(m3 - nm3);
    m0 = nm0; m1 = nm1; m2 = nm2; m3 = nm3;
    sp0 *= sc0; sp1 *= sc1; sp2 *= sc2; sp3 *= sc3;
    float asc = (hagg == 0) ? sc0 : (hagg == 1) ? sc1 : (hagg == 2) ? sc2 : sc3;
    acc.x *= asc; acc.y *= asc; acc.z *= asc; acc.w *= asc;
    // wait for prior chunk's sw reads before overwriting (WAR; rare D>64 path)
    asm volatile("s_waitcnt lgkmcnt(0)" ::: "memory");
    if (valid) {
      float e0v = __expf(a0 - nm0), e1v = __expf(a1 - nm1);
      float e2v = __expf(a2 - nm2), e3v = __expf(a3 - nm3);
      sp0 += e0v; sp1 += e1v; sp2 += e2v; sp3 += e3v;
      sw[lane * 4 + 0] = e0v; sw[lane * 4 + 1] = e1v;
      sw[lane * 4 + 2] = e2v; sw[lane * 4 + 3] = e3v;
    }
    // make LDS writes visible to all lanes of this wave (lockstep, no barrier)
    asm volatile("s_waitcnt lgkmcnt(0)" ::: "memory");
    // weighted aggregation: 2 edges (2 x 512B rows) per wave-iteration.
    const int npair = (cnt + 1) >> 1;
    #pragma unroll 4
    for (int i = 0; i < npair; ++i) {
      int e = 2 * i + half;
      bool ev = e < cnt;
      int sd = __shfl(s_reg, ev ? e : (cnt - 1));
      float w = ev ? sw[e * 4 + hagg] : 0.f;
      float4 v = xl4[(size_t)sd * 32 + cl];
      acc.x = fmaf(w, v.x, acc.x);
      acc.y = fmaf(w, v.y, acc.y);
      acc.z = fmaf(w, v.z, acc.z);
      acc.w = fmaf(w, v.w, acc.w);
    }
  }

  // final expsum reduction per head
  #pragma unroll
  for (int mask = 1; mask < 64; mask <<= 1) {
    sp0 += __shfl_xor(sp0, mask);
    sp1 += __shfl_xor(sp1, mask);
    sp2 += __shfl_xor(sp2, mask);
    sp3 += __shfl_xor(sp3, mask);
  }
  float sum = (hagg == 0) ? sp0 : (hagg == 1) ? sp1 : (hagg == 2) ? sp2 : sp3;
  float rs = 1.f / sum;
  // combine even-edge and odd-edge partial accumulators across wave halves
  acc.x += __shfl_xor(acc.x, 32);
  acc.y += __shfl_xor(acc.y, 32);
  acc.z += __shfl_xor(acc.z, 32);
  acc.w += __shfl_xor(acc.w, 32);
  if (half == 0) {
    float4 bv = ((const float4*)bias)[cl];
    float4 o;
    o.x = fmaf(acc.x, rs, bv.x);
    o.y = fmaf(acc.y, rs, bv.y);
    o.z = fmaf(acc.z, rs, bv.z);
    o.w = fmaf(acc.w, rs, bv.w);
    ((float4*)out)[(size_t)n * 32 + cl] = o;
  }
}

// ======================================================================
extern "C" void kernel_launch(void* const* d_in, const int* in_sizes, int n_in,
                              void* d_out, int out_size, void* d_ws, size_t ws_size,
                              hipStream_t stream) {
  const float* x      = (const float*)d_in[0];
  const float* W      = (const float*)d_in[1];
  const float* attn_j = (const float*)d_in[2];
  const float* attn_i = (const float*)d_in[3];
  const float* bias   = (const float*)d_in[4];
  const int*   eidx   = (const int*)d_in[5];

  const int N = in_sizes[0] / 128;
  const int E = in_sizes[5] / 2;
  const int Et = E + N;
  const int B = (N + BKT_NODES - 1) / BKT_NODES;   // 391 for N=50000
  const int* src = eidx;
  const int* dst = eidx + E;
  float* out = (float*)d_out;

  // workspace carve (256B aligned)
  char* p = (char*)d_ws;
  auto alloc = [&](size_t bytes) -> char* {
    char* q = p;
    p += (bytes + 255) & ~(size_t)255;
    return q;
  };
  float*    xl      = (float*)alloc((size_t)N * 128 * sizeof(float));
  float*    aj      = (float*)alloc((size_t)N * 4 * sizeof(float));
  float*    ai      = (float*)alloc((size_t)N * 4 * sizeof(float));
  float*    bj      = (float*)alloc((size_t)N * 4 * sizeof(float));
  float*    bi      = (float*)alloc((size_t)N * 4 * sizeof(float));
  int*      gcnt    = (int*)alloc((size_t)(B + 1) * sizeof(int));
  int*      bin_off = (int*)alloc((size_t)(B + 1) * sizeof(int));
  int*      bcur    = (int*)alloc((size_t)B * sizeof(int));
  int*      off     = (int*)alloc((size_t)(N + 1) * sizeof(int));
  int*      csr     = (int*)alloc((size_t)Et * sizeof(int));
  unsigned* bins    = (unsigned*)alloc((size_t)E * sizeof(unsigned));

  const int ebpb = 4096;  // edges per block in hist/scatter
  // 1. GEMM + fused node scores
  gemm_node<<<(N + 63) / 64, 256, 0, stream>>>(x, W, attn_j, attn_i, xl, aj, ai, N);
  // 2. double-gather resolution + gcnt zero
  node_prep<<<(N + 255) / 256, 256, 0, stream>>>(aj, ai, src, dst, bj, bi, gcnt, B, N);
  // 3-6. CSR build via bucket counting sort
  bucket_hist<<<(E + ebpb - 1) / ebpb, 256, 0, stream>>>(dst, gcnt, E);
  bucket_scan<<<1, 512, 0, stream>>>(gcnt, bin_off, bcur, B);
  bucket_scatter<<<(E + ebpb - 1) / ebpb, 256, 0, stream>>>(src, dst, bcur, bins, E);
  bucket_csr<<<B, 256, 0, stream>>>(bins, bin_off, off, csr, N, B, Et);
  // 7. online softmax + aggregation (4 nodes per 256-thr block, barrier-free)
  gat_node<<<(N + 3) / 4, 256, 0, stream>>>(xl, bj, bi, off, csr, bias, out, N);
}